// Round 18
// baseline (744.038 us; speedup 1.0000x reference)
//
#include <hip/hip_runtime.h>
#include <cmath>

#define E_ 64
#define H_ 4
#define B_ 2
#define R_ 1225
#define C_ 512
#define EPS 1e-5f

__device__ __forceinline__ float elu1(float a) { return a > 0.f ? a + 1.f : __expf(a); }

typedef float f32x4 __attribute__((ext_vector_type(4)));
typedef short bf16x8 __attribute__((ext_vector_type(8)));
typedef short bf16x4 __attribute__((ext_vector_type(4)));

__device__ __forceinline__ unsigned short f2bf(float f) {
    union { float f; unsigned u; } c; c.f = f;
    unsigned u = c.u + 0x7FFFu + ((c.u >> 16) & 1u);   // RNE
    return (unsigned short)(u >> 16);
}

// lean round-to-nearest (ties up): 2 VALU ops
__device__ __forceinline__ unsigned short f2bf_rn(float f) {
    union { float f; unsigned u; } c; c.f = f;
    return (unsigned short)((c.u + 0x8000u) >> 16);
}

__device__ __forceinline__ float bf2f(unsigned short s) {
    union { unsigned u; float f; } c; c.u = ((unsigned)s) << 16;
    return c.f;
}

// tanh-approx GELU, sigmoid form; log2e folded into polynomial, v_exp2 + v_rcp
__device__ __forceinline__ float gelu_fast(float a) {
    const float u2 = a * (-2.3022150f - 0.10294366f * a * a);
    return a * __builtin_amdgcn_rcpf(1.f + __builtin_amdgcn_exp2f(u2));
}

// ---------------------------------------------------------------------------
// Pipeline (round 18): r17 + ffn LDS squeezed to exactly 40960B -> 4 blk/CU
// (pads dropped: r14 proved LDS bank conflicts are off ffn's critical path;
// s_ln aliases s_g, disjoint lifetimes) + exp2-folded GELU.
// ---------------------------------------------------------------------------

#define SXR 520   // 512+8 pad

__global__ __launch_bounds__(512, 2) void row_attn(
    const float* __restrict__ x,
    const float* __restrict__ wq, const float* __restrict__ bq,
    const float* __restrict__ wk, const float* __restrict__ bk,
    const float* __restrict__ wv, const float* __restrict__ bv,
    const float* __restrict__ wo, const float* __restrict__ bo,
    const float* __restrict__ lng, const float* __restrict__ lnb,
    short* __restrict__ hout)
{
    const int r = blockIdx.x;
    const int b = blockIdx.y;
    const int t = threadIdx.x;      // 0..511 == c
    const int w = t >> 6;
    const int l = t & 63;
    const int lr = l & 15;
    const int lq = l >> 4;

    __shared__ short s_xT[E_][SXR];
    __shared__ short s_kb[4][SXR];
    __shared__ float s_upart[2][H_][E_];
    __shared__ float s_ktv[E_];
    __shared__ float s_wok[E_][H_];
    __shared__ float s_qm[H_];
    __shared__ float s_sk[H_];
    __shared__ float s_S1[H_];
    __shared__ float red_q[8][H_];
    __shared__ float red_k[8][H_];
    __shared__ float red_k2[8][H_];
    __shared__ float s_cst[16];

    if (t < 16) {
        const int h = t & 3;
        const int kind = t >> 2;
        const float* wm = (kind < 2) ? wq : wk;
        const float* vm = (kind & 1) ? lnb : lng;
        float acc = 0.f;
        for (int e = 0; e < E_; ++e) acc += wm[h * E_ + e] * vm[e];
        s_cst[t] = acc;
    }
    __syncthreads();

    const size_t RC = (size_t)R_ * C_;
    const float* xbase = x + (size_t)b * E_ * RC + (size_t)r * C_;

    float qs[H_];
    float aq[H_], ak[H_], ak2[H_];
    {
        const float* xp = xbase + t;
        float s = 0.f, ss = 0.f;
        float dq[H_] = {0.f, 0.f, 0.f, 0.f};
        float dk[H_] = {0.f, 0.f, 0.f, 0.f};
        #pragma unroll 16
        for (int e = 0; e < E_; ++e) {
            const float xv = xp[(size_t)e * RC];
            s += xv; ss += xv * xv;
            const float t1 = lng[e] * xv;
            #pragma unroll
            for (int h = 0; h < H_; ++h) { dq[h] += wq[h * E_ + e] * t1; dk[h] += wk[h * E_ + e] * t1; }
            s_xT[e][t] = (short)f2bf(xv);
        }
        const float mu = s * (1.f / E_);
        const float rstd = rsqrtf(ss * (1.f / E_) - mu * mu + EPS);
        const float mr = mu * rstd;
        #pragma unroll
        for (int h = 0; h < H_; ++h) {
            const float qv = elu1(rstd * dq[h] - mr * s_cst[h]     + s_cst[4 + h]  + bq[h]);
            const float kv = elu1(rstd * dk[h] - mr * s_cst[8 + h] + s_cst[12 + h] + bk[h]);
            qs[h] = qv;
            aq[h] = qv; ak[h] = kv; ak2[h] = kv * mr;
            s_kb[h][t] = (short)f2bf(kv * rstd);
        }
    }
    __syncthreads();

    {
        const int et = w & 3;
        const int kh = w >> 2;
        f32x4 uacc; uacc[0] = uacc[1] = uacc[2] = uacc[3] = 0.f;
        #pragma unroll
        for (int ks = 0; ks < 8; ++ks) {
            const int co = kh * 256 + ks * 32 + lq * 8;
            bf16x8 af;
            #pragma unroll
            for (int i = 0; i < 8; ++i) af[i] = 0;
            if (lr < 4) af = *reinterpret_cast<const bf16x8*>(&s_kb[lr][co]);
            const bf16x8 bf = *reinterpret_cast<const bf16x8*>(&s_xT[et * 16 + lr][co]);
            uacc = __builtin_amdgcn_mfma_f32_16x16x32_bf16(af, bf, uacc, 0, 0, 0);
        }
        if (lq == 0) {
            #pragma unroll
            for (int i = 0; i < 4; ++i) s_upart[kh][i][et * 16 + lr] = uacc[i];
        }
    }

    #pragma unroll
    for (int h = 0; h < H_; ++h) {
        #pragma unroll
        for (int off = 32; off; off >>= 1) {
            aq[h] += __shfl_xor(aq[h], off, 64);
            ak[h] += __shfl_xor(ak[h], off, 64);
            ak2[h] += __shfl_xor(ak2[h], off, 64);
        }
    }
    if (l == 0) {
        #pragma unroll
        for (int h = 0; h < H_; ++h) { red_q[w][h] = aq[h]; red_k[w][h] = ak[h]; red_k2[w][h] = ak2[h]; }
    }
    __syncthreads();
    if (t < H_) {
        float sq = 0.f, sk = 0.f, s1 = 0.f;
        #pragma unroll
        for (int w2 = 0; w2 < 8; ++w2) { sq += red_q[w2][t]; sk += red_k[w2][t]; s1 += red_k2[w2][t]; }
        s_qm[t] = sq * (1.f / C_);
        s_sk[t] = sk;
        s_S1[t] = s1;
    }
    __syncthreads();
    if (t < H_ * E_) {
        const int h = t >> 6, e = t & 63;
        const float m1 = s_upart[0][h][e] + s_upart[1][h][e];
        s_upart[0][h][e] = lng[e] * (m1 - s_S1[h]) + lnb[e] * s_sk[h];
    }
    __syncthreads();
    if (t < E_) {
        const int h = t >> 4;
        float acc = 0.f;
        #pragma unroll
        for (int e = 0; e < E_; ++e) acc += wv[t * E_ + e] * s_upart[0][h][e];
        s_ktv[t] = acc / s_sk[h] + bv[t];
    }
    __syncthreads();
    if (t < E_) {
        #pragma unroll
        for (int h = 0; h < H_; ++h) {
            float acc = 0.f;
            #pragma unroll
            for (int d = 0; d < 16; ++d) acc += wo[t * E_ + h * 16 + d] * s_ktv[h * 16 + d];
            s_wok[t][h] = acc;
        }
    }
    __syncthreads();

    {
        float qn[H_];
        #pragma unroll
        for (int h = 0; h < H_; ++h) qn[h] = qs[h] / s_qm[h];
        short* hp = hout + ((size_t)((size_t)b * R_ + r) * C_ + t) * E_;
        #pragma unroll
        for (int e8 = 0; e8 < 8; ++e8) {
            bf16x8 o;
            #pragma unroll
            for (int i = 0; i < 8; ++i) {
                const int e = e8 * 8 + i;
                float tt = bo[e];
                #pragma unroll
                for (int h = 0; h < H_; ++h) tt += qn[h] * s_wok[e][h];
                o[i] = (short)f2bf(bf2f((unsigned short)s_xT[e][t]) + tt);
            }
            *reinterpret_cast<bf16x8*>(hp + e8 * 8) = o;
        }
    }
}

// ---------------------------------------------------------------------------
// col_stats (unchanged r16 layouts).
// ---------------------------------------------------------------------------
#define SX 264

__global__ __launch_bounds__(256, 3) void col_stats(
    const short* __restrict__ hbuf,
    const float* __restrict__ wq, const float* __restrict__ bq,
    const float* __restrict__ wk, const float* __restrict__ bk,
    const float* __restrict__ wv, const float* __restrict__ bv,
    const float* __restrict__ wo,
    const float* __restrict__ lng, const float* __restrict__ lnb,
    unsigned short* __restrict__ qbuf, float* __restrict__ wokq)
{
    const int c = blockIdx.x;
    const int b = blockIdx.y;
    const int t = threadIdx.x;
    const int w = t >> 6;
    const int l = t & 63;
    const int lr = l & 15;
    const int lq = l >> 4;

    __shared__ short s_xT[E_][SX];
    __shared__ short s_kb[4][SX];
    __shared__ float s_u[H_][E_];
    __shared__ float s_ktv[E_];
    __shared__ float s_wok[E_][H_];
    __shared__ float s_qm[H_];
    __shared__ float s_sk[H_];
    __shared__ float s_S1[H_];
    __shared__ float red_q[4][H_];
    __shared__ float red_k[4][H_];
    __shared__ float red_k2[4][H_];
    __shared__ float s_cst[16];

    if (t < 16) {
        const int h = t & 3;
        const int kind = t >> 2;
        const float* wm = (kind < 2) ? wq : wk;
        const float* vm = (kind & 1) ? lnb : lng;
        float acc = 0.f;
        for (int e = 0; e < E_; ++e) acc += wm[h * E_ + e] * vm[e];
        s_cst[t] = acc;
    }
    __syncthreads();

    const size_t CE = (size_t)C_ * E_;
    const short* hp0 = hbuf + (size_t)b * R_ * CE + (size_t)c * E_;

    float aq[H_]  = {0.f, 0.f, 0.f, 0.f};
    float ak[H_]  = {0.f, 0.f, 0.f, 0.f};
    float ak2[H_] = {0.f, 0.f, 0.f, 0.f};
    f32x4 uacc; uacc[0] = uacc[1] = uacc[2] = uacc[3] = 0.f;

    #pragma unroll 1
    for (int it = 0; it < 5; ++it) {
        const int rr = it * 256 + t;
        if (rr < R_) {
            const short* pp = hp0 + (size_t)rr * CE;
            bf16x8 hv8[8];
            #pragma unroll
            for (int g = 0; g < 8; ++g) hv8[g] = *reinterpret_cast<const bf16x8*>(pp + g * 8);
            float s = 0.f, ss = 0.f;
            float dq[H_] = {0.f, 0.f, 0.f, 0.f};
            float dk[H_] = {0.f, 0.f, 0.f, 0.f};
            #pragma unroll
            for (int g = 0; g < 8; ++g) {
                #pragma unroll
                for (int i = 0; i < 8; ++i) {
                    const int e = g * 8 + i;
                    const float xv = bf2f((unsigned short)hv8[g][i]);
                    s += xv; ss += xv * xv;
                    const float t1 = lng[e] * xv;
                    #pragma unroll
                    for (int h = 0; h < H_; ++h) { dq[h] += wq[h * E_ + e] * t1; dk[h] += wk[h * E_ + e] * t1; }
                    s_xT[e][t] = hv8[g][i];
                }
            }
            const float mu = s * (1.f / E_);
            const float rstd = rsqrtf(ss * (1.f / E_) - mu * mu + EPS);
            const float mr = mu * rstd;
            float qv[H_];
            #pragma unroll
            for (int h = 0; h < H_; ++h) {
                qv[h] = elu1(rstd * dq[h] - mr * s_cst[h]     + s_cst[4 + h]  + bq[h]);
                const float kv = elu1(rstd * dk[h] - mr * s_cst[8 + h] + s_cst[12 + h] + bk[h]);
                aq[h] += qv[h]; ak[h] += kv; ak2[h] += kv * mr;
                s_kb[h][t] = (short)f2bf(kv * rstd);
            }
            uint2 qp;
            qp.x = ((unsigned)f2bf(qv[1]) << 16) | f2bf(qv[0]);
            qp.y = ((unsigned)f2bf(qv[3]) << 16) | f2bf(qv[2]);
            *reinterpret_cast<uint2*>(qbuf + (((size_t)b * R_ + rr) * C_ + c) * 4) = qp;
        } else {
            #pragma unroll
            for (int e = 0; e < E_; ++e) s_xT[e][t] = 0;
            #pragma unroll
            for (int h = 0; h < H_; ++h) s_kb[h][t] = 0;
        }
        __syncthreads();
        #pragma unroll
        for (int ks = 0; ks < 8; ++ks) {
            bf16x8 af;
            #pragma unroll
            for (int i = 0; i < 8; ++i) af[i] = 0;
            if (lr < 4) af = *reinterpret_cast<const bf16x8*>(&s_kb[lr][ks * 32 + lq * 8]);
            const bf16x8 bf = *reinterpret_cast<const bf16x8*>(&s_xT[w * 16 + lr][ks * 32 + lq * 8]);
            uacc = __builtin_amdgcn_mfma_f32_16x16x32_bf16(af, bf, uacc, 0, 0, 0);
        }
        __syncthreads();
    }

    #pragma unroll
    for (int h = 0; h < H_; ++h) {
        #pragma unroll
        for (int off = 32; off; off >>= 1) {
            aq[h] += __shfl_xor(aq[h], off, 64);
            ak[h] += __shfl_xor(ak[h], off, 64);
            ak2[h] += __shfl_xor(ak2[h], off, 64);
        }
    }
    if (l == 0) {
        #pragma unroll
        for (int h = 0; h < H_; ++h) { red_q[w][h] = aq[h]; red_k[w][h] = ak[h]; red_k2[w][h] = ak2[h]; }
    }
    __syncthreads();
    if (t < H_) {
        float sq = 0.f, sk = 0.f, s1 = 0.f;
        #pragma unroll
        for (int w2 = 0; w2 < 4; ++w2) { sq += red_q[w2][t]; sk += red_k[w2][t]; s1 += red_k2[w2][t]; }
        s_qm[t] = sq * (1.f / R_);
        s_sk[t] = sk;
        s_S1[t] = s1;
    }
    __syncthreads();
    if (lq == 0) {
        const int e = w * 16 + lr;
        #pragma unroll
        for (int i = 0; i < 4; ++i)
            s_u[i][e] = lng[e] * (uacc[i] - s_S1[i]) + lnb[e] * s_sk[i];
    }
    __syncthreads();
    if (t < E_) {
        const int h = t >> 4;
        float acc = 0.f;
        #pragma unroll
        for (int e = 0; e < E_; ++e) acc += wv[t * E_ + e] * s_u[h][e];
        s_ktv[t] = acc / s_sk[h] + bv[t];
    }
    __syncthreads();
    if (t < E_) {
        #pragma unroll
        for (int h = 0; h < H_; ++h) {
            float acc = 0.f;
            #pragma unroll
            for (int d = 0; d < 16; ++d) acc += wo[t * E_ + h * 16 + d] * s_ktv[h * 16 + d];
            s_wok[t][h] = acc;
        }
    }
    __syncthreads();

    {
        const int e = t >> 2, h = t & 3;
        wokq[(((size_t)b * 64 + e) * C_ + c) * 4 + h] = s_wok[e][h] / s_qm[h];
    }
}

// ---------------------------------------------------------------------------
// prep_weights (unchanged).
// ---------------------------------------------------------------------------
__global__ __launch_bounds__(256) void prep_weights(
    const float* __restrict__ w1, const float* __restrict__ w2,
    short* __restrict__ w1b, short* __restrict__ w2b)
{
    const int i = blockIdx.x * 256 + threadIdx.x;
    if (i < 16384) w1b[i] = (short)f2bf(w1[i]);
    else           w2b[i - 16384] = (short)f2bf(w2[i - 16384]);
}

// ---------------------------------------------------------------------------
// ffn_mfma v8: LDS exactly 40960B -> 4 blocks/CU.
// Map: s_g [0,32768) stride 256 | s_a [32768,40960) stride 64 |
//      s_ln alias s_g [0,2048)   (dies at 1b barrier, s_g born after)
//      s_o  alias s_g [0,17408)  (born after GEMM2 reads, SO=68)
// Pads removed: r14 measured LDS bank conflicts OFF the critical path.
// ---------------------------------------------------------------------------
#define SA 64
#define SG 256
#define SO 68

__global__ __launch_bounds__(256) void ffn_mfma(
    const short* __restrict__ hbuf,
    const unsigned short* __restrict__ qbuf, const float* __restrict__ wokq,
    const float* __restrict__ cbo,
    const float* __restrict__ lng, const float* __restrict__ lnb,
    const short* __restrict__ w1b, const float* __restrict__ b1,
    const short* __restrict__ w2b, const float* __restrict__ b2,
    float* __restrict__ out)
{
    __shared__ __align__(16) char smem[40960];
    short* s_g = (short*)smem;
    short* s_a = (short*)(smem + 32768);
    float* s_o = (float*)smem;           // alias s_g
    float* s_ln = (float*)smem;          // alias s_g (disjoint lifetime)

    const int t = threadIdx.x;
    const int w = t >> 6;
    const int l = t & 63;
    const int lr = l & 15;
    const int lq = l >> 4;

    const int bid = blockIdx.x;
    const int cb  = bid & 7;
    const int rem = bid >> 3;
    const int r   = rem % R_;
    const int b   = rem / R_;
    const int c0  = cb * 64;

    const short* tile = hbuf + ((size_t)((size_t)b * R_ + r) * C_ + c0) * E_;

    const int m  = l;            // position within tile (c = c0 + m)
    const int eb = w * 16;       // e-range [eb, eb+16)
    float hc[16];
    {
        const short* hp = tile + (size_t)m * E_ + eb;
        const bf16x8 v0 = *reinterpret_cast<const bf16x8*>(hp);
        const bf16x8 v1 = *reinterpret_cast<const bf16x8*>(hp + 8);
        const uint2 qp = *reinterpret_cast<const uint2*>(
            qbuf + (((size_t)b * R_ + r) * C_ + (c0 + m)) * 4);
        float qv[4];
        qv[0] = bf2f((unsigned short)(qp.x & 0xFFFF));
        qv[1] = bf2f((unsigned short)(qp.x >> 16));
        qv[2] = bf2f((unsigned short)(qp.y & 0xFFFF));
        qv[3] = bf2f((unsigned short)(qp.y >> 16));
        const float4* wq4 = reinterpret_cast<const float4*>(wokq)
                          + ((size_t)b * 64 + eb) * C_ + (c0 + m);
        float s = 0.f, ss = 0.f;
        #pragma unroll
        for (int i = 0; i < 16; ++i) {
            const int e = eb + i;
            const float4 f4 = wq4[(size_t)i * C_];
            const float hv = bf2f((unsigned short)(i < 8 ? v0[i] : v1[i - 8]));
            hc[i] = hv + cbo[e] + qv[0] * f4.x + qv[1] * f4.y + qv[2] * f4.z + qv[3] * f4.w;
            s += hc[i]; ss += hc[i] * hc[i];
        }
        s_ln[w * 64 + m]       = s;
        s_ln[256 + w * 64 + m] = ss;
    }
    __syncthreads();

    {
        const float s  = s_ln[m] + s_ln[64 + m] + s_ln[128 + m] + s_ln[192 + m];
        const float ss = s_ln[256 + m] + s_ln[320 + m] + s_ln[384 + m] + s_ln[448 + m];
        const float mu = s * (1.f / 64.f);
        const float rstd = rsqrtf(ss * (1.f / 64.f) - mu * mu + EPS);
        bf16x8 o0, o1;
        #pragma unroll
        for (int i = 0; i < 8; ++i) {
            const int e = eb + i;
            o0[i] = (short)f2bf_rn((hc[i] - mu) * rstd * lng[e] + lnb[e]);
        }
        #pragma unroll
        for (int i = 0; i < 8; ++i) {
            const int e = eb + 8 + i;
            o1[i] = (short)f2bf_rn((hc[8 + i] - mu) * rstd * lng[e] + lnb[e]);
        }
        __syncthreads();   // s_ln reads complete before s_a write epoch overlaps GEMM1's s_g
        *reinterpret_cast<bf16x8*>(&s_a[m * SA + eb])     = o0;
        *reinterpret_cast<bf16x8*>(&s_a[m * SA + eb + 8]) = o1;
    }
    __syncthreads();

    {
        bf16x8 bfr[4][2];
        #pragma unroll
        for (int mt = 0; mt < 4; ++mt)
            #pragma unroll
            for (int ks = 0; ks < 2; ++ks)
                bfr[mt][ks] = *reinterpret_cast<const bf16x8*>(
                    &s_a[(mt * 16 + lr) * SA + ks * 32 + lq * 8]);

        #pragma unroll
        for (int nn = 0; nn < 4; ++nn) {
            const int jt = w * 4 + nn;
            bf16x8 afr[2];
            #pragma unroll
            for (int ks = 0; ks < 2; ++ks)
                afr[ks] = *reinterpret_cast<const bf16x8*>(
                    w1b + (size_t)(jt * 16 + lr) * 64 + ks * 32 + lq * 8);
            f32x4 acc[4];
            #pragma unroll
            for (int mt = 0; mt < 4; ++mt) { acc[mt][0]=0.f; acc[mt][1]=0.f; acc[mt][2]=0.f; acc[mt][3]=0.f; }
            #pragma unroll
            for (int ks = 0; ks < 2; ++ks)
                #pragma unroll
                for (int mt = 0; mt < 4; ++mt)
                    acc[mt] = __builtin_amdgcn_mfma_f32_16x16x32_bf16(afr[ks], bfr[mt][ks], acc[mt], 0, 0, 0);

            const float4 b1v = *reinterpret_cast<const float4*>(&b1[jt * 16 + lq * 4]);
            const float* b1p = (const float*)&b1v;
            #pragma unroll
            for (int mt = 0; mt < 4; ++mt) {
                const int mm = mt * 16 + lr;
                bf16x4 pk;
                #pragma unroll
                for (int i = 0; i < 4; ++i) {
                    const float aa = acc[mt][i] + b1p[i];
                    pk[i] = (short)f2bf_rn(gelu_fast(aa));
                }
                *reinterpret_cast<bf16x4*>(&s_g[mm * SG + jt * 16 + lq * 4]) = pk;
            }
        }
    }
    __syncthreads();

    {
        f32x4 acc2[4];
        #pragma unroll
        for (int mt = 0; mt < 4; ++mt) { acc2[mt][0]=0.f; acc2[mt][1]=0.f; acc2[mt][2]=0.f; acc2[mt][3]=0.f; }
        const int n = w * 16 + lr;
        #pragma unroll
        for (int ks = 0; ks < 8; ++ks) {
            const bf16x8 bfr = *reinterpret_cast<const bf16x8*>(
                w2b + (size_t)n * 256 + ks * 32 + lq * 8);
            #pragma unroll
            for (int mt = 0; mt < 4; ++mt) {
                const bf16x8 af = *reinterpret_cast<const bf16x8*>(
                    &s_g[(mt * 16 + lr) * SG + ks * 32 + lq * 8]);
                acc2[mt] = __builtin_amdgcn_mfma_f32_16x16x32_bf16(af, bfr, acc2[mt], 0, 0, 0);
            }
        }
        __syncthreads();   // s_g reads complete before s_o (alias) writes
        #pragma unroll
        for (int mt = 0; mt < 4; ++mt)
            #pragma unroll
            for (int i = 0; i < 4; ++i)
                s_o[(mt * 16 + lq * 4 + i) * SO + n] = acc2[mt][i];
    }
    __syncthreads();

    {
        const size_t RC = (size_t)R_ * C_;
        float* op = out + (size_t)b * E_ * RC + (size_t)r * C_ + (c0 + m);
        #pragma unroll
        for (int j = 0; j < 4; ++j) {
            const float4 so4 = *reinterpret_cast<const float4*>(
                &s_o[m * SO + eb + j * 4]);
            const float* sop = (const float*)&so4;
            #pragma unroll
            for (int i = 0; i < 4; ++i) {
                const int e = eb + j * 4 + i;
                op[(size_t)e * RC] = hc[j * 4 + i] + b2[e] + sop[i];
            }
        }
    }
}

extern "C" void kernel_launch(void* const* d_in, const int* in_sizes, int n_in,
                              void* d_out, int out_size, void* d_ws, size_t ws_size,
                              hipStream_t stream) {
    const float* x      = (const float*)d_in[0];
    const float* row_wq = (const float*)d_in[1];
    const float* row_bq = (const float*)d_in[2];
    const float* row_wk = (const float*)d_in[3];
    const float* row_bk = (const float*)d_in[4];
    const float* row_wv = (const float*)d_in[5];
    const float* row_bv = (const float*)d_in[6];
    const float* row_wo = (const float*)d_in[7];
    const float* row_bo = (const float*)d_in[8];
    const float* col_wq = (const float*)d_in[9];
    const float* col_bq = (const float*)d_in[10];
    const float* col_wk = (const float*)d_in[11];
    const float* col_bk = (const float*)d_in[12];
    const float* col_wv = (const float*)d_in[13];
    const float* col_bv = (const float*)d_in[14];
    const float* col_wo = (const float*)d_in[15];
    const float* col_bo = (const float*)d_in[16];
    const float* rn_g   = (const float*)d_in[17];
    const float* rn_b   = (const float*)d_in[18];
    const float* cn_g   = (const float*)d_in[19];
    const float* cn_b   = (const float*)d_in[20];
    const float* fn_g   = (const float*)d_in[21];
    const float* fn_b   = (const float*)d_in[22];
    const float* w1     = (const float*)d_in[23];
    const float* b1     = (const float*)d_in[24];
    const float* w2     = (const float*)d_in[25];
    const float* b2     = (const float*)d_in[26];

    const size_t n_h   = (size_t)B_ * R_ * C_ * E_;          // bf16 elements
    const size_t n_q   = (size_t)B_ * R_ * C_ * 4;           // bf16 elements
    const size_t n_wok = (size_t)B_ * 64 * C_ * 4;           // f32 elements
    const size_t need  = n_h * 2 + n_q * 2 + n_wok * 4 + 2 * 16384 * 2;
    if (ws_size < need) return;

    short* hbuf = (short*)d_ws;
    unsigned short* qbuf = (unsigned short*)(hbuf + n_h);
    float* wokq = (float*)(qbuf + n_q);
    short* w1b = (short*)(wokq + n_wok);
    short* w2b = w1b + 16384;

    row_attn<<<dim3(R_, B_), 512, 0, stream>>>(
        x, row_wq, row_bq, row_wk, row_bk, row_wv, row_bv, row_wo, row_bo,
        rn_g, rn_b, hbuf);
    prep_weights<<<128, 256, 0, stream>>>(w1, w2, w1b, w2b);
    col_stats<<<dim3(C_, B_), 256, 0, stream>>>(
        hbuf, col_wq, col_bq, col_wk, col_bk, col_wv, col_bv, col_wo,
        cn_g, cn_b, qbuf, wokq);
    ffn_mfma<<<B_ * R_ * 8, 256, 0, stream>>>(
        hbuf, qbuf, wokq, col_bo, fn_g, fn_b, w1b, b1, w2b, b2, (float*)d_out);
}

// Round 19
// 613.083 us; speedup vs baseline: 1.2136x; 1.2136x over previous
//
#include <hip/hip_runtime.h>
#include <cmath>

#define E_ 64
#define H_ 4
#define B_ 2
#define R_ 1225
#define C_ 512
#define EPS 1e-5f

__device__ __forceinline__ float elu1(float a) { return a > 0.f ? a + 1.f : __expf(a); }

typedef float f32x4 __attribute__((ext_vector_type(4)));
typedef short bf16x8 __attribute__((ext_vector_type(8)));
typedef short bf16x4 __attribute__((ext_vector_type(4)));

__device__ __forceinline__ unsigned short f2bf(float f) {
    union { float f; unsigned u; } c; c.f = f;
    unsigned u = c.u + 0x7FFFu + ((c.u >> 16) & 1u);   // RNE
    return (unsigned short)(u >> 16);
}

// lean round-to-nearest (ties up): 2 VALU ops
__device__ __forceinline__ unsigned short f2bf_rn(float f) {
    union { float f; unsigned u; } c; c.f = f;
    return (unsigned short)((c.u + 0x8000u) >> 16);
}

__device__ __forceinline__ float bf2f(unsigned short s) {
    union { unsigned u; float f; } c; c.u = ((unsigned)s) << 16;
    return c.f;
}

// tanh-approx GELU, sigmoid form; log2e folded into polynomial, v_exp2 + v_rcp
__device__ __forceinline__ float gelu_fast(float a) {
    const float u2 = a * (-2.3022150f - 0.10294366f * a * a);
    return a * __builtin_amdgcn_rcpf(1.f + __builtin_amdgcn_exp2f(u2));
}

// ---------------------------------------------------------------------------
// Pipeline (round 19) = round 17 (best known, 616us) + exp2-folded GELU.
// r18 refuted: LDS squeeze to 40960 did NOT raise occupancy (HW reserve),
// and pad removal at power-of-2 strides made conflicts 1.6e8 (critical-path).
// ffn LDS layout restored: SA=72 / SG=264 / SO=68, smem 51200, separate s_ln.
// ---------------------------------------------------------------------------

#define SXR 520   // 512+8 pad

__global__ __launch_bounds__(512, 2) void row_attn(
    const float* __restrict__ x,
    const float* __restrict__ wq, const float* __restrict__ bq,
    const float* __restrict__ wk, const float* __restrict__ bk,
    const float* __restrict__ wv, const float* __restrict__ bv,
    const float* __restrict__ wo, const float* __restrict__ bo,
    const float* __restrict__ lng, const float* __restrict__ lnb,
    short* __restrict__ hout)
{
    const int r = blockIdx.x;
    const int b = blockIdx.y;
    const int t = threadIdx.x;      // 0..511 == c
    const int w = t >> 6;
    const int l = t & 63;
    const int lr = l & 15;
    const int lq = l >> 4;

    __shared__ short s_xT[E_][SXR];
    __shared__ short s_kb[4][SXR];
    __shared__ float s_upart[2][H_][E_];
    __shared__ float s_ktv[E_];
    __shared__ float s_wok[E_][H_];
    __shared__ float s_qm[H_];
    __shared__ float s_sk[H_];
    __shared__ float s_S1[H_];
    __shared__ float red_q[8][H_];
    __shared__ float red_k[8][H_];
    __shared__ float red_k2[8][H_];
    __shared__ float s_cst[16];

    if (t < 16) {
        const int h = t & 3;
        const int kind = t >> 2;
        const float* wm = (kind < 2) ? wq : wk;
        const float* vm = (kind & 1) ? lnb : lng;
        float acc = 0.f;
        for (int e = 0; e < E_; ++e) acc += wm[h * E_ + e] * vm[e];
        s_cst[t] = acc;
    }
    __syncthreads();

    const size_t RC = (size_t)R_ * C_;
    const float* xbase = x + (size_t)b * E_ * RC + (size_t)r * C_;

    float qs[H_];
    float aq[H_], ak[H_], ak2[H_];
    {
        const float* xp = xbase + t;
        float s = 0.f, ss = 0.f;
        float dq[H_] = {0.f, 0.f, 0.f, 0.f};
        float dk[H_] = {0.f, 0.f, 0.f, 0.f};
        #pragma unroll 16
        for (int e = 0; e < E_; ++e) {
            const float xv = xp[(size_t)e * RC];
            s += xv; ss += xv * xv;
            const float t1 = lng[e] * xv;
            #pragma unroll
            for (int h = 0; h < H_; ++h) { dq[h] += wq[h * E_ + e] * t1; dk[h] += wk[h * E_ + e] * t1; }
            s_xT[e][t] = (short)f2bf(xv);
        }
        const float mu = s * (1.f / E_);
        const float rstd = rsqrtf(ss * (1.f / E_) - mu * mu + EPS);
        const float mr = mu * rstd;
        #pragma unroll
        for (int h = 0; h < H_; ++h) {
            const float qv = elu1(rstd * dq[h] - mr * s_cst[h]     + s_cst[4 + h]  + bq[h]);
            const float kv = elu1(rstd * dk[h] - mr * s_cst[8 + h] + s_cst[12 + h] + bk[h]);
            qs[h] = qv;
            aq[h] = qv; ak[h] = kv; ak2[h] = kv * mr;
            s_kb[h][t] = (short)f2bf(kv * rstd);
        }
    }
    __syncthreads();

    {
        const int et = w & 3;
        const int kh = w >> 2;
        f32x4 uacc; uacc[0] = uacc[1] = uacc[2] = uacc[3] = 0.f;
        #pragma unroll
        for (int ks = 0; ks < 8; ++ks) {
            const int co = kh * 256 + ks * 32 + lq * 8;
            bf16x8 af;
            #pragma unroll
            for (int i = 0; i < 8; ++i) af[i] = 0;
            if (lr < 4) af = *reinterpret_cast<const bf16x8*>(&s_kb[lr][co]);
            const bf16x8 bf = *reinterpret_cast<const bf16x8*>(&s_xT[et * 16 + lr][co]);
            uacc = __builtin_amdgcn_mfma_f32_16x16x32_bf16(af, bf, uacc, 0, 0, 0);
        }
        if (lq == 0) {
            #pragma unroll
            for (int i = 0; i < 4; ++i) s_upart[kh][i][et * 16 + lr] = uacc[i];
        }
    }

    #pragma unroll
    for (int h = 0; h < H_; ++h) {
        #pragma unroll
        for (int off = 32; off; off >>= 1) {
            aq[h] += __shfl_xor(aq[h], off, 64);
            ak[h] += __shfl_xor(ak[h], off, 64);
            ak2[h] += __shfl_xor(ak2[h], off, 64);
        }
    }
    if (l == 0) {
        #pragma unroll
        for (int h = 0; h < H_; ++h) { red_q[w][h] = aq[h]; red_k[w][h] = ak[h]; red_k2[w][h] = ak2[h]; }
    }
    __syncthreads();
    if (t < H_) {
        float sq = 0.f, sk = 0.f, s1 = 0.f;
        #pragma unroll
        for (int w2 = 0; w2 < 8; ++w2) { sq += red_q[w2][t]; sk += red_k[w2][t]; s1 += red_k2[w2][t]; }
        s_qm[t] = sq * (1.f / C_);
        s_sk[t] = sk;
        s_S1[t] = s1;
    }
    __syncthreads();
    if (t < H_ * E_) {
        const int h = t >> 6, e = t & 63;
        const float m1 = s_upart[0][h][e] + s_upart[1][h][e];
        s_upart[0][h][e] = lng[e] * (m1 - s_S1[h]) + lnb[e] * s_sk[h];
    }
    __syncthreads();
    if (t < E_) {
        const int h = t >> 4;
        float acc = 0.f;
        #pragma unroll
        for (int e = 0; e < E_; ++e) acc += wv[t * E_ + e] * s_upart[0][h][e];
        s_ktv[t] = acc / s_sk[h] + bv[t];
    }
    __syncthreads();
    if (t < E_) {
        #pragma unroll
        for (int h = 0; h < H_; ++h) {
            float acc = 0.f;
            #pragma unroll
            for (int d = 0; d < 16; ++d) acc += wo[t * E_ + h * 16 + d] * s_ktv[h * 16 + d];
            s_wok[t][h] = acc;
        }
    }
    __syncthreads();

    {
        float qn[H_];
        #pragma unroll
        for (int h = 0; h < H_; ++h) qn[h] = qs[h] / s_qm[h];
        short* hp = hout + ((size_t)((size_t)b * R_ + r) * C_ + t) * E_;
        #pragma unroll
        for (int e8 = 0; e8 < 8; ++e8) {
            bf16x8 o;
            #pragma unroll
            for (int i = 0; i < 8; ++i) {
                const int e = e8 * 8 + i;
                float tt = bo[e];
                #pragma unroll
                for (int h = 0; h < H_; ++h) tt += qn[h] * s_wok[e][h];
                o[i] = (short)f2bf(bf2f((unsigned short)s_xT[e][t]) + tt);
            }
            *reinterpret_cast<bf16x8*>(hp + e8 * 8) = o;
        }
    }
}

// ---------------------------------------------------------------------------
// col_stats (unchanged r16/r17).
// ---------------------------------------------------------------------------
#define SX 264

__global__ __launch_bounds__(256, 3) void col_stats(
    const short* __restrict__ hbuf,
    const float* __restrict__ wq, const float* __restrict__ bq,
    const float* __restrict__ wk, const float* __restrict__ bk,
    const float* __restrict__ wv, const float* __restrict__ bv,
    const float* __restrict__ wo,
    const float* __restrict__ lng, const float* __restrict__ lnb,
    unsigned short* __restrict__ qbuf, float* __restrict__ wokq)
{
    const int c = blockIdx.x;
    const int b = blockIdx.y;
    const int t = threadIdx.x;
    const int w = t >> 6;
    const int l = t & 63;
    const int lr = l & 15;
    const int lq = l >> 4;

    __shared__ short s_xT[E_][SX];
    __shared__ short s_kb[4][SX];
    __shared__ float s_u[H_][E_];
    __shared__ float s_ktv[E_];
    __shared__ float s_wok[E_][H_];
    __shared__ float s_qm[H_];
    __shared__ float s_sk[H_];
    __shared__ float s_S1[H_];
    __shared__ float red_q[4][H_];
    __shared__ float red_k[4][H_];
    __shared__ float red_k2[4][H_];
    __shared__ float s_cst[16];

    if (t < 16) {
        const int h = t & 3;
        const int kind = t >> 2;
        const float* wm = (kind < 2) ? wq : wk;
        const float* vm = (kind & 1) ? lnb : lng;
        float acc = 0.f;
        for (int e = 0; e < E_; ++e) acc += wm[h * E_ + e] * vm[e];
        s_cst[t] = acc;
    }
    __syncthreads();

    const size_t CE = (size_t)C_ * E_;
    const short* hp0 = hbuf + (size_t)b * R_ * CE + (size_t)c * E_;

    float aq[H_]  = {0.f, 0.f, 0.f, 0.f};
    float ak[H_]  = {0.f, 0.f, 0.f, 0.f};
    float ak2[H_] = {0.f, 0.f, 0.f, 0.f};
    f32x4 uacc; uacc[0] = uacc[1] = uacc[2] = uacc[3] = 0.f;

    #pragma unroll 1
    for (int it = 0; it < 5; ++it) {
        const int rr = it * 256 + t;
        if (rr < R_) {
            const short* pp = hp0 + (size_t)rr * CE;
            bf16x8 hv8[8];
            #pragma unroll
            for (int g = 0; g < 8; ++g) hv8[g] = *reinterpret_cast<const bf16x8*>(pp + g * 8);
            float s = 0.f, ss = 0.f;
            float dq[H_] = {0.f, 0.f, 0.f, 0.f};
            float dk[H_] = {0.f, 0.f, 0.f, 0.f};
            #pragma unroll
            for (int g = 0; g < 8; ++g) {
                #pragma unroll
                for (int i = 0; i < 8; ++i) {
                    const int e = g * 8 + i;
                    const float xv = bf2f((unsigned short)hv8[g][i]);
                    s += xv; ss += xv * xv;
                    const float t1 = lng[e] * xv;
                    #pragma unroll
                    for (int h = 0; h < H_; ++h) { dq[h] += wq[h * E_ + e] * t1; dk[h] += wk[h * E_ + e] * t1; }
                    s_xT[e][t] = hv8[g][i];
                }
            }
            const float mu = s * (1.f / E_);
            const float rstd = rsqrtf(ss * (1.f / E_) - mu * mu + EPS);
            const float mr = mu * rstd;
            float qv[H_];
            #pragma unroll
            for (int h = 0; h < H_; ++h) {
                qv[h] = elu1(rstd * dq[h] - mr * s_cst[h]     + s_cst[4 + h]  + bq[h]);
                const float kv = elu1(rstd * dk[h] - mr * s_cst[8 + h] + s_cst[12 + h] + bk[h]);
                aq[h] += qv[h]; ak[h] += kv; ak2[h] += kv * mr;
                s_kb[h][t] = (short)f2bf(kv * rstd);
            }
            uint2 qp;
            qp.x = ((unsigned)f2bf(qv[1]) << 16) | f2bf(qv[0]);
            qp.y = ((unsigned)f2bf(qv[3]) << 16) | f2bf(qv[2]);
            *reinterpret_cast<uint2*>(qbuf + (((size_t)b * R_ + rr) * C_ + c) * 4) = qp;
        } else {
            #pragma unroll
            for (int e = 0; e < E_; ++e) s_xT[e][t] = 0;
            #pragma unroll
            for (int h = 0; h < H_; ++h) s_kb[h][t] = 0;
        }
        __syncthreads();
        #pragma unroll
        for (int ks = 0; ks < 8; ++ks) {
            bf16x8 af;
            #pragma unroll
            for (int i = 0; i < 8; ++i) af[i] = 0;
            if (lr < 4) af = *reinterpret_cast<const bf16x8*>(&s_kb[lr][ks * 32 + lq * 8]);
            const bf16x8 bf = *reinterpret_cast<const bf16x8*>(&s_xT[w * 16 + lr][ks * 32 + lq * 8]);
            uacc = __builtin_amdgcn_mfma_f32_16x16x32_bf16(af, bf, uacc, 0, 0, 0);
        }
        __syncthreads();
    }

    #pragma unroll
    for (int h = 0; h < H_; ++h) {
        #pragma unroll
        for (int off = 32; off; off >>= 1) {
            aq[h] += __shfl_xor(aq[h], off, 64);
            ak[h] += __shfl_xor(ak[h], off, 64);
            ak2[h] += __shfl_xor(ak2[h], off, 64);
        }
    }
    if (l == 0) {
        #pragma unroll
        for (int h = 0; h < H_; ++h) { red_q[w][h] = aq[h]; red_k[w][h] = ak[h]; red_k2[w][h] = ak2[h]; }
    }
    __syncthreads();
    if (t < H_) {
        float sq = 0.f, sk = 0.f, s1 = 0.f;
        #pragma unroll
        for (int w2 = 0; w2 < 4; ++w2) { sq += red_q[w2][t]; sk += red_k[w2][t]; s1 += red_k2[w2][t]; }
        s_qm[t] = sq * (1.f / R_);
        s_sk[t] = sk;
        s_S1[t] = s1;
    }
    __syncthreads();
    if (lq == 0) {
        const int e = w * 16 + lr;
        #pragma unroll
        for (int i = 0; i < 4; ++i)
            s_u[i][e] = lng[e] * (uacc[i] - s_S1[i]) + lnb[e] * s_sk[i];
    }
    __syncthreads();
    if (t < E_) {
        const int h = t >> 4;
        float acc = 0.f;
        #pragma unroll
        for (int e = 0; e < E_; ++e) acc += wv[t * E_ + e] * s_u[h][e];
        s_ktv[t] = acc / s_sk[h] + bv[t];
    }
    __syncthreads();
    if (t < E_) {
        #pragma unroll
        for (int h = 0; h < H_; ++h) {
            float acc = 0.f;
            #pragma unroll
            for (int d = 0; d < 16; ++d) acc += wo[t * E_ + h * 16 + d] * s_ktv[h * 16 + d];
            s_wok[t][h] = acc;
        }
    }
    __syncthreads();

    {
        const int e = t >> 2, h = t & 3;
        wokq[(((size_t)b * 64 + e) * C_ + c) * 4 + h] = s_wok[e][h] / s_qm[h];
    }
}

// ---------------------------------------------------------------------------
// prep_weights (unchanged).
// ---------------------------------------------------------------------------
__global__ __launch_bounds__(256) void prep_weights(
    const float* __restrict__ w1, const float* __restrict__ w2,
    short* __restrict__ w1b, short* __restrict__ w2b)
{
    const int i = blockIdx.x * 256 + threadIdx.x;
    if (i < 16384) w1b[i] = (short)f2bf(w1[i]);
    else           w2b[i - 16384] = (short)f2bf(w2[i - 16384]);
}

// ---------------------------------------------------------------------------
// ffn_mfma v9 = r17 layout (SA=72/SG=264/SO=68, smem 51200, separate s_ln)
// + exp2-folded GELU. hc in registers end-to-end; coalesced qbuf/wokq.
// LDS map: s_g [0,33792) | s_a [33792,43008) | s_o [33792,51200) alias |
//          s_ln [43008,45056) (dead before s_o writes)
// ---------------------------------------------------------------------------
#define SA 72
#define SG 264
#define SO 68

__global__ __launch_bounds__(256) void ffn_mfma(
    const short* __restrict__ hbuf,
    const unsigned short* __restrict__ qbuf, const float* __restrict__ wokq,
    const float* __restrict__ cbo,
    const float* __restrict__ lng, const float* __restrict__ lnb,
    const short* __restrict__ w1b, const float* __restrict__ b1,
    const short* __restrict__ w2b, const float* __restrict__ b2,
    float* __restrict__ out)
{
    __shared__ __align__(16) char smem[51200];
    short* s_g = (short*)smem;
    short* s_a = (short*)(smem + 33792);
    float* s_o = (float*)(smem + 33792);
    float* s_ln = (float*)(smem + 43008);

    const int t = threadIdx.x;
    const int w = t >> 6;
    const int l = t & 63;
    const int lr = l & 15;
    const int lq = l >> 4;

    const int bid = blockIdx.x;
    const int cb  = bid & 7;
    const int rem = bid >> 3;
    const int r   = rem % R_;
    const int b   = rem / R_;
    const int c0  = cb * 64;

    const short* tile = hbuf + ((size_t)((size_t)b * R_ + r) * C_ + c0) * E_;

    const int m  = l;            // position within tile (c = c0 + m)
    const int eb = w * 16;       // e-range [eb, eb+16)
    float hc[16];
    {
        const short* hp = tile + (size_t)m * E_ + eb;
        const bf16x8 v0 = *reinterpret_cast<const bf16x8*>(hp);
        const bf16x8 v1 = *reinterpret_cast<const bf16x8*>(hp + 8);
        const uint2 qp = *reinterpret_cast<const uint2*>(
            qbuf + (((size_t)b * R_ + r) * C_ + (c0 + m)) * 4);
        float qv[4];
        qv[0] = bf2f((unsigned short)(qp.x & 0xFFFF));
        qv[1] = bf2f((unsigned short)(qp.x >> 16));
        qv[2] = bf2f((unsigned short)(qp.y & 0xFFFF));
        qv[3] = bf2f((unsigned short)(qp.y >> 16));
        const float4* wq4 = reinterpret_cast<const float4*>(wokq)
                          + ((size_t)b * 64 + eb) * C_ + (c0 + m);
        float s = 0.f, ss = 0.f;
        #pragma unroll
        for (int i = 0; i < 16; ++i) {
            const int e = eb + i;
            const float4 f4 = wq4[(size_t)i * C_];
            const float hv = bf2f((unsigned short)(i < 8 ? v0[i] : v1[i - 8]));
            hc[i] = hv + cbo[e] + qv[0] * f4.x + qv[1] * f4.y + qv[2] * f4.z + qv[3] * f4.w;
            s += hc[i]; ss += hc[i] * hc[i];
        }
        s_ln[w * 64 + m]       = s;
        s_ln[256 + w * 64 + m] = ss;
    }
    __syncthreads();

    {
        const float s  = s_ln[m] + s_ln[64 + m] + s_ln[128 + m] + s_ln[192 + m];
        const float ss = s_ln[256 + m] + s_ln[320 + m] + s_ln[384 + m] + s_ln[448 + m];
        const float mu = s * (1.f / 64.f);
        const float rstd = rsqrtf(ss * (1.f / 64.f) - mu * mu + EPS);
        bf16x8 o0, o1;
        #pragma unroll
        for (int i = 0; i < 8; ++i) {
            const int e = eb + i;
            o0[i] = (short)f2bf_rn((hc[i] - mu) * rstd * lng[e] + lnb[e]);
        }
        #pragma unroll
        for (int i = 0; i < 8; ++i) {
            const int e = eb + 8 + i;
            o1[i] = (short)f2bf_rn((hc[8 + i] - mu) * rstd * lng[e] + lnb[e]);
        }
        *reinterpret_cast<bf16x8*>(&s_a[m * SA + eb])     = o0;
        *reinterpret_cast<bf16x8*>(&s_a[m * SA + eb + 8]) = o1;
    }
    __syncthreads();

    {
        bf16x8 bfr[4][2];
        #pragma unroll
        for (int mt = 0; mt < 4; ++mt)
            #pragma unroll
            for (int ks = 0; ks < 2; ++ks)
                bfr[mt][ks] = *reinterpret_cast<const bf16x8*>(
                    &s_a[(mt * 16 + lr) * SA + ks * 32 + lq * 8]);

        #pragma unroll
        for (int nn = 0; nn < 4; ++nn) {
            const int jt = w * 4 + nn;
            bf16x8 afr[2];
            #pragma unroll
            for (int ks = 0; ks < 2; ++ks)
                afr[ks] = *reinterpret_cast<const bf16x8*>(
                    w1b + (size_t)(jt * 16 + lr) * 64 + ks * 32 + lq * 8);
            f32x4 acc[4];
            #pragma unroll
            for (int mt = 0; mt < 4; ++mt) { acc[mt][0]=0.f; acc[mt][1]=0.f; acc[mt][2]=0.f; acc[mt][3]=0.f; }
            #pragma unroll
            for (int ks = 0; ks < 2; ++ks)
                #pragma unroll
                for (int mt = 0; mt < 4; ++mt)
                    acc[mt] = __builtin_amdgcn_mfma_f32_16x16x32_bf16(afr[ks], bfr[mt][ks], acc[mt], 0, 0, 0);

            const float4 b1v = *reinterpret_cast<const float4*>(&b1[jt * 16 + lq * 4]);
            const float* b1p = (const float*)&b1v;
            #pragma unroll
            for (int mt = 0; mt < 4; ++mt) {
                const int mm = mt * 16 + lr;
                bf16x4 pk;
                #pragma unroll
                for (int i = 0; i < 4; ++i) {
                    const float aa = acc[mt][i] + b1p[i];
                    pk[i] = (short)f2bf_rn(gelu_fast(aa));
                }
                *reinterpret_cast<bf16x4*>(&s_g[mm * SG + jt * 16 + lq * 4]) = pk;
            }
        }
    }
    __syncthreads();

    {
        f32x4 acc2[4];
        #pragma unroll
        for (int mt = 0; mt < 4; ++mt) { acc2[mt][0]=0.f; acc2[mt][1]=0.f; acc2[mt][2]=0.f; acc2[mt][3]=0.f; }
        const int n = w * 16 + lr;
        #pragma unroll
        for (int ks = 0; ks < 8; ++ks) {
            const bf16x8 bfr = *reinterpret_cast<const bf16x8*>(
                w2b + (size_t)n * 256 + ks * 32 + lq * 8);
            #pragma unroll
            for (int mt = 0; mt < 4; ++mt) {
                const bf16x8 af = *reinterpret_cast<const bf16x8*>(
                    &s_g[(mt * 16 + lr) * SG + ks * 32 + lq * 8]);
                acc2[mt] = __builtin_amdgcn_mfma_f32_16x16x32_bf16(af, bfr, acc2[mt], 0, 0, 0);
            }
        }
        __syncthreads();   // s_g reads complete before s_o (alias) writes
        #pragma unroll
        for (int mt = 0; mt < 4; ++mt)
            #pragma unroll
            for (int i = 0; i < 4; ++i)
                s_o[(mt * 16 + lq * 4 + i) * SO + n] = acc2[mt][i];
    }
    __syncthreads();

    {
        const size_t RC = (size_t)R_ * C_;
        float* op = out + (size_t)b * E_ * RC + (size_t)r * C_ + (c0 + m);
        #pragma unroll
        for (int j = 0; j < 4; ++j) {
            const float4 so4 = *reinterpret_cast<const float4*>(
                &s_o[m * SO + eb + j * 4]);
            const float* sop = (const float*)&so4;
            #pragma unroll
            for (int i = 0; i < 4; ++i) {
                const int e = eb + j * 4 + i;
                op[(size_t)e * RC] = hc[j * 4 + i] + b2[e] + sop[i];
            }
        }
    }
}

extern "C" void kernel_launch(void* const* d_in, const int* in_sizes, int n_in,
                              void* d_out, int out_size, void* d_ws, size_t ws_size,
                              hipStream_t stream) {
    const float* x      = (const float*)d_in[0];
    const float* row_wq = (const float*)d_in[1];
    const float* row_bq = (const float*)d_in[2];
    const float* row_wk = (const float*)d_in[3];
    const float* row_bk = (const float*)d_in[4];
    const float* row_wv = (const float*)d_in[5];
    const float* row_bv = (const float*)d_in[6];
    const float* row_wo = (const float*)d_in[7];
    const float* row_bo = (const float*)d_in[8];
    const float* col_wq = (const float*)d_in[9];
    const float* col_bq = (const float*)d_in[10];
    const float* col_wk = (const float*)d_in[11];
    const float* col_bk = (const float*)d_in[12];
    const float* col_wv = (const float*)d_in[13];
    const float* col_bv = (const float*)d_in[14];
    const float* col_wo = (const float*)d_in[15];
    const float* col_bo = (const float*)d_in[16];
    const float* rn_g   = (const float*)d_in[17];
    const float* rn_b   = (const float*)d_in[18];
    const float* cn_g   = (const float*)d_in[19];
    const float* cn_b   = (const float*)d_in[20];
    const float* fn_g   = (const float*)d_in[21];
    const float* fn_b   = (const float*)d_in[22];
    const float* w1     = (const float*)d_in[23];
    const float* b1     = (const float*)d_in[24];
    const float* w2     = (const float*)d_in[25];
    const float* b2     = (const float*)d_in[26];

    const size_t n_h   = (size_t)B_ * R_ * C_ * E_;          // bf16 elements
    const size_t n_q   = (size_t)B_ * R_ * C_ * 4;           // bf16 elements
    const size_t n_wok = (size_t)B_ * 64 * C_ * 4;           // f32 elements
    const size_t need  = n_h * 2 + n_q * 2 + n_wok * 4 + 2 * 16384 * 2;
    if (ws_size < need) return;

    short* hbuf = (short*)d_ws;
    unsigned short* qbuf = (unsigned short*)(hbuf + n_h);
    float* wokq = (float*)(qbuf + n_q);
    short* w1b = (short*)(wokq + n_wok);
    short* w2b = w1b + 16384;

    row_attn<<<dim3(R_, B_), 512, 0, stream>>>(
        x, row_wq, row_bq, row_wk, row_bk, row_wv, row_bv, row_wo, row_bo,
        rn_g, rn_b, hbuf);
    prep_weights<<<128, 256, 0, stream>>>(w1, w2, w1b, w2b);
    col_stats<<<dim3(C_, B_), 256, 0, stream>>>(
        hbuf, col_wq, col_bq, col_wk, col_bk, col_wv, col_bv, col_wo,
        cn_g, cn_b, qbuf, wokq);
    ffn_mfma<<<B_ * R_ * 8, 256, 0, stream>>>(
        hbuf, qbuf, wokq, col_bo, fn_g, fn_b, w1b, b1, w2b, b2, (float*)d_out);
}